// Round 11
// baseline (32.495 us; speedup 1.0000x reference)
//
#include <hip/hip_runtime.h>
#include <math.h>

#define B_ 4096
#define D_ 256
#define C_ 64
#define BD (B_*D_)

typedef __attribute__((ext_vector_type(8))) short bf16x8;
typedef __attribute__((ext_vector_type(4))) float f32x4;

__device__ __forceinline__ float wave_reduce_sum(float v) {
    #pragma unroll
    for (int off = 1; off < 64; off <<= 1) v += __shfl_xor(v, off);
    return v;
}

__device__ __forceinline__ unsigned cvtpk(float lo, float hi) {
    unsigned r;
    asm volatile("v_cvt_pk_bf16_f32 %0, %1, %2" : "=v"(r) : "v"(lo), "v"(hi));
    return r;
}

// ---- fused MFMA kernel: grid = 64 conds x 4 col-tiles = 256 blocks ----
// Block (cond,ct): y[:, ct*64 .. ct*64+63] for ALL samples of cond.
// W rows read exactly once globally (disjoint 64KB per block).
__global__ __launch_bounds__(256, 1) void k_main(const float* __restrict__ W,
                                                 const float* __restrict__ b,
                                                 const float* __restrict__ x,
                                                 const int* __restrict__ c,
                                                 float* __restrict__ out,
                                                 float* __restrict__ l1p,
                                                 float* __restrict__ xsqp,
                                                 int* __restrict__ cnt) {
    int hw = blockIdx.x;
    int bid = (hw & 7) * 32 + (hw >> 3);    // XCD swizzle: cond's 4 blocks share an XCD (x-gather locality)
    int cond = bid >> 2;
    int ct = bid & 3;
    int tid = threadIdx.x;
    int wv = tid >> 6, lane = tid & 63;
    int g = lane >> 4, fr = lane & 15;
    int r = tid >> 2, ch = tid & 3;         // W staging: row 0..63, k-chunk 0..3

    // ---- early independent loads: x stripe, c, W slab0, bias ----
    const float4* x4 = (const float4*)x;
    float4 xv[4];
    #pragma unroll
    for (int t = 0; t < 4; ++t) xv[t] = x4[bid * 1024 + t * 256 + tid];
    int4 cvq[4];
    #pragma unroll
    for (int t = 0; t < 4; ++t) cvq[t] = ((const int4*)c)[t * 256 + tid];
    // this block's W rows: cond*65536 + (ct*64 + r)*256 floats; slab kk: float4 idx kk*8 + ch*2
    const float4* Wr4 = (const float4*)(W + (size_t)cond * 65536 + (size_t)ct * 64 * 256) + (size_t)r * 64;
    float4 wA0 = Wr4[ch * 2], wA1 = Wr4[ch * 2 + 1];       // slab 0
    float4 wB0, wB1;
    float bias_s = b[cond * 256 + ct * 64 + wv * 16 + fr];

    __shared__ unsigned Xl[128 * 128];       // up to 128 samples x 512B bf16 rows (XOR swizzled)
    __shared__ unsigned Wl[2][64 * 20];      // dbuf W slab: 64 rows x 80B (32 k bf16 + pad)
    __shared__ float part_x[4];
    __shared__ float part_w[4];
    __shared__ int slist[128];
    __shared__ int nlist;
    if (tid == 0) nlist = 0;

    // ---- x copy to out tail + sumsq partial ----
    float2* dst = (float2*)(out + BD + 2);
    float s = 0.f;
    #pragma unroll
    for (int t = 0; t < 4; ++t) {
        int xi = bid * 1024 + t * 256 + tid;
        dst[2 * xi]     = make_float2(xv[t].x, xv[t].y);
        dst[2 * xi + 1] = make_float2(xv[t].z, xv[t].w);
        s += xv[t].x * xv[t].x + xv[t].y * xv[t].y + xv[t].z * xv[t].z + xv[t].w * xv[t].w;
    }
    s = wave_reduce_sum(s);
    if (lane == 0) part_x[wv] = s;
    __syncthreads();                         // nlist init + part_x visible

    // ---- full scan: all 4096 samples, keep those with c == cond ----
    #pragma unroll
    for (int t = 0; t < 4; ++t) {
        int4 q = cvq[t];
        int base = 4 * (t * 256 + tid);
        if (q.x == cond) { int p = atomicAdd(&nlist, 1); if (p < 128) slist[p] = base; }
        if (q.y == cond) { int p = atomicAdd(&nlist, 1); if (p < 128) slist[p] = base + 1; }
        if (q.z == cond) { int p = atomicAdd(&nlist, 1); if (p < 128) slist[p] = base + 2; }
        if (q.w == cond) { int p = atomicAdd(&nlist, 1); if (p < 128) slist[p] = base + 3; }
    }
    __syncthreads();
    int n = min(nlist, 128);
    int mts = (n + 15) >> 4;                 // up to 8 sample-tiles
    if (tid == 0) {
        xsqp[bid] = (part_x[0] + part_x[1]) + (part_x[2] + part_x[3]);
        if (ct == 0) cnt[cond] = n;
    }

    // ---- stage X: gather fp32 -> bf16 LDS, XOR swizzle ((row&7)<<4) ----
    for (int u = tid; u < n * 64; u += 256) {
        int si = u >> 6, v = u & 63;
        int sg = slist[si];
        float4 q = x4[(size_t)sg * 64 + v];
        int off = (v * 8) ^ ((si & 7) << 4);
        Xl[si * 128 + (off >> 2)]     = cvtpk(q.x, q.y);
        Xl[si * 128 + (off >> 2) + 1] = cvtpk(q.z, q.w);
    }

    // ---- stage W slab0, prefetch slab1 ----
    float l1acc = 0.f;
    {
        uint4 pk;
        pk.x = cvtpk(wA0.x, wA0.y); pk.y = cvtpk(wA0.z, wA0.w);
        pk.z = cvtpk(wA1.x, wA1.y); pk.w = cvtpk(wA1.z, wA1.w);
        *(uint4*)(&Wl[0][r * 20 + ch * 4]) = pk;
        l1acc += fabsf(wA0.x) + fabsf(wA0.y) + fabsf(wA0.z) + fabsf(wA0.w)
               + fabsf(wA1.x) + fabsf(wA1.y) + fabsf(wA1.z) + fabsf(wA1.w);
    }
    wB0 = Wr4[8 + ch * 2]; wB1 = Wr4[8 + ch * 2 + 1];
    __syncthreads();

    // ---- K loop: 8 slabs, double-buffered ----
    f32x4 acc[8];
    #pragma unroll
    for (int mt = 0; mt < 8; ++mt) acc[mt] = (f32x4){0.f, 0.f, 0.f, 0.f};

    #pragma unroll
    for (int kk = 0; kk < 8; ++kk) {
        const unsigned* Wb = Wl[kk & 1];
        bf16x8 bfr = *(const bf16x8*)(Wb + (wv * 16 + fr) * 20 + g * 4);
        #pragma unroll
        for (int mt = 0; mt < 8; ++mt) if (mt < mts) {
            int row = mt * 16 + fr;
            bf16x8 afr = *(const bf16x8*)((const char*)Xl + row * 512 + ((kk * 64 + g * 16) ^ ((row & 7) << 4)));
            acc[mt] = __builtin_amdgcn_mfma_f32_16x16x32_bf16(afr, bfr, acc[mt], 0, 0, 0);
        }
        if (kk < 7) {
            float4 w0 = (kk & 1) ? wA0 : wB0;
            float4 w1 = (kk & 1) ? wA1 : wB1;
            uint4 pk;
            pk.x = cvtpk(w0.x, w0.y); pk.y = cvtpk(w0.z, w0.w);
            pk.z = cvtpk(w1.x, w1.y); pk.w = cvtpk(w1.z, w1.w);
            *(uint4*)(&Wl[(kk + 1) & 1][r * 20 + ch * 4]) = pk;
            l1acc += fabsf(w0.x) + fabsf(w0.y) + fabsf(w0.z) + fabsf(w0.w)
                   + fabsf(w1.x) + fabsf(w1.y) + fabsf(w1.z) + fabsf(w1.w);
            if (kk < 6) {
                if (kk & 1) { wA0 = Wr4[(kk + 2) * 8 + ch * 2]; wA1 = Wr4[(kk + 2) * 8 + ch * 2 + 1]; }
                else        { wB0 = Wr4[(kk + 2) * 8 + ch * 2]; wB1 = Wr4[(kk + 2) * 8 + ch * 2 + 1]; }
            }
            __syncthreads();
        }
    }

    // ---- W L1 partial (every block: disjoint W rows) ----
    float a = wave_reduce_sum(l1acc);
    if (lane == 0) part_w[wv] = a;
    __syncthreads();
    if (tid == 0) l1p[bid] = (part_w[0] + part_w[1]) + (part_w[2] + part_w[3]);

    // ---- bias add + store unnormalized y ----
    #pragma unroll
    for (int mt = 0; mt < 8; ++mt) if (mt < mts) {
        #pragma unroll
        for (int j = 0; j < 4; ++j) {
            int row = mt * 16 + g * 4 + j;
            if (row < n) {
                int sg = slist[row];
                out[(size_t)sg * 256 + ct * 64 + wv * 16 + fr] = acc[mt][j] + bias_s;
            }
        }
    }
}

// ---- blocks 0..1023: row L2-normalize (wave per row) ----
// ---- block 1024: finalize embed_norm and mask_norm ----
__global__ __launch_bounds__(256) void k_fin(float* __restrict__ out,
                                             const float* __restrict__ xsqp,
                                             const float* __restrict__ l1p,
                                             const int* __restrict__ cnt) {
    int tid = threadIdx.x;
    int wv = tid >> 6, lane = tid & 63;
    if (blockIdx.x == 1024) {
        __shared__ float part[4];
        float s = xsqp[tid];
        s = wave_reduce_sum(s);
        if (lane == 0) part[wv] = s;
        __syncthreads();
        if (tid < 64) {
            float l1 = (l1p[tid * 4 + 0] + l1p[tid * 4 + 1]) + (l1p[tid * 4 + 2] + l1p[tid * 4 + 3]);
            float mv = l1 * (float)cnt[tid];
            mv = wave_reduce_sum(mv);
            if (tid == 0) out[BD] = mv;                                               // mask_norm
        }
        if (tid == 0) out[BD + 1] = sqrtf((part[0] + part[1]) + (part[2] + part[3])); // embed_norm
        return;
    }
    int rowv = blockIdx.x * 4 + wv;          // 4096 rows, wave per row
    float4* p = (float4*)out + (size_t)rowv * 64 + lane;
    float4 v = *p;
    float s = v.x * v.x + v.y * v.y + v.z * v.z + v.w * v.w;
    s = wave_reduce_sum(s);
    float inv = 1.0f / fmaxf(sqrtf(s), 1e-10f);
    v.x *= inv; v.y *= inv; v.z *= inv; v.w *= inv;
    *p = v;
}

extern "C" void kernel_launch(void* const* d_in, const int* in_sizes, int n_in,
                              void* d_out, int out_size, void* d_ws, size_t ws_size,
                              hipStream_t stream) {
    const float* x = (const float*)d_in[0];
    const float* W = (const float*)d_in[1];
    const float* b = (const float*)d_in[2];
    const int*   c = (const int*)d_in[3];
    float* out = (float*)d_out;

    float* xsqp = (float*)d_ws;           // 256
    float* l1p  = xsqp + 256;             // 256
    int*   cnt  = (int*)(l1p + 256);      // 64

    k_main<<<256, 256, 0, stream>>>(W, b, x, c, out, l1p, xsqp, cnt);
    k_fin<<<1025, 256, 0, stream>>>(out, xsqp, l1p, cnt);
}

// Round 12
// 19.310 us; speedup vs baseline: 1.6828x; 1.6828x over previous
//
#include <hip/hip_runtime.h>
#include <math.h>

#define B_ 4096
#define D_ 256
#define C_ 64
#define BD (B_*D_)

typedef __attribute__((ext_vector_type(8))) short bf16x8;
typedef __attribute__((ext_vector_type(4))) float f32x4;

__device__ __forceinline__ float wave_reduce_sum(float v) {
    #pragma unroll
    for (int off = 1; off < 64; off <<= 1) v += __shfl_xor(v, off);
    return v;
}

__device__ __forceinline__ unsigned cvtpk(float lo, float hi) {
    unsigned r;
    asm volatile("v_cvt_pk_bf16_f32 %0, %1, %2" : "=v"(r) : "v"(lo), "v"(hi));
    return r;
}

// ---- MFMA kernel: grid = 64 conds x 2 col-halves x 4 sample-slices = 512 (2/CU) ----
// Block (cond,ct,sl): y[samples = sl (mod 4) of cond, cols ct*128..+127].
__global__ __launch_bounds__(256, 2) void k_main(const float* __restrict__ W,
                                                 const float* __restrict__ b,
                                                 const float* __restrict__ x,
                                                 const int* __restrict__ c,
                                                 float* __restrict__ out,
                                                 float* __restrict__ l1p,
                                                 float* __restrict__ xsqp,
                                                 int* __restrict__ cnt4) {
    int hw = blockIdx.x;
    int bid = (hw & 7) * 64 + (hw >> 3);    // XCD swizzle: a cond's 8 blocks share an XCD
    int cond = bid >> 3;
    int ct = (bid >> 2) & 1;
    int sl = bid & 3;
    int tid = threadIdx.x;
    int wv = tid >> 6, lane = tid & 63;
    int g = lane >> 4, fr = lane & 15;
    int wr = tid >> 1, wh = tid & 1;        // W staging: row 0..127, half 0..1

    // ---- early independent loads: x stripe, c slice, W slab0, bias ----
    const float4* x4 = (const float4*)x;
    float4 xv0 = x4[bid * 512 + tid];
    float4 xv1 = x4[bid * 512 + 256 + tid];
    int4 cvq[4];
    #pragma unroll
    for (int t = 0; t < 4; ++t) cvq[t] = ((const int4*)c)[t * 256 + tid];
    // this block's W rows: cond*65536 + (ct*128 + wr)*256 floats; thread covers half wh
    const float4* Wt4 = (const float4*)(W + (size_t)cond * 65536) + (size_t)(ct * 128 + wr) * 64 + wh * 4;
    float4 wA[4], wB[4];
    #pragma unroll
    for (int j = 0; j < 4; ++j) wA[j] = Wt4[j];           // slab 0 (k 0..31)
    float bias0 = b[cond * 256 + ct * 128 + wv * 32 + fr];
    float bias1 = b[cond * 256 + ct * 128 + wv * 32 + 16 + fr];

    __shared__ unsigned Xl[48 * 128];        // up to 48 samples x 512B bf16 (XOR swizzled) = 24KB
    __shared__ unsigned Wl[2][128 * 20];     // dbuf W slab: 128 rows x 80B = 20KB
    __shared__ float part_x[4];
    __shared__ float part_w[4];
    __shared__ int slist[48];
    __shared__ int nlist;
    if (tid == 0) nlist = 0;

    // ---- x copy to out tail + sumsq partial ----
    float2* dst = (float2*)(out + BD + 2);
    int xi = bid * 512 + tid;
    dst[2 * xi]             = make_float2(xv0.x, xv0.y);
    dst[2 * xi + 1]         = make_float2(xv0.z, xv0.w);
    dst[2 * (xi + 256)]     = make_float2(xv1.x, xv1.y);
    dst[2 * (xi + 256) + 1] = make_float2(xv1.z, xv1.w);
    float s = xv0.x * xv0.x + xv0.y * xv0.y + xv0.z * xv0.z + xv0.w * xv0.w
            + xv1.x * xv1.x + xv1.y * xv1.y + xv1.z * xv1.z + xv1.w * xv1.w;
    s = wave_reduce_sum(s);
    if (lane == 0) part_x[wv] = s;
    __syncthreads();                         // nlist init + part_x visible

    // ---- slice scan: slice sl owns samples i == sl (mod 4) (1024 candidates) ----
    #pragma unroll
    for (int t = 0; t < 4; ++t) {
        int4 q = cvq[t];
        int cc = (sl == 0) ? q.x : (sl == 1) ? q.y : (sl == 2) ? q.z : q.w;
        if (cc == cond) {
            int p = atomicAdd(&nlist, 1);
            if (p < 48) slist[p] = 4 * (t * 256 + tid) + sl;
        }
    }
    // pin W slab0 in regs (loads issued early; don't let compiler sink them)
    #pragma unroll
    for (int j = 0; j < 4; ++j)
        asm volatile("" : "+v"(wA[j].x), "+v"(wA[j].y), "+v"(wA[j].z), "+v"(wA[j].w));
    __syncthreads();
    int n = min(nlist, 48);
    int mts = (n + 15) >> 4;                 // 0..3 sample-tiles
    if (tid == 0) {
        xsqp[bid] = (part_x[0] + part_x[1]) + (part_x[2] + part_x[3]);
        if (ct == 0) cnt4[cond * 4 + sl] = n;
    }

    // ---- stage X: batched gather (slist pre-read -> all loads in flight) ----
    int sgr[12];
    #pragma unroll
    for (int k = 0; k < 12; ++k) sgr[k] = slist[wv + 4 * k];
    #pragma unroll
    for (int k = 0; k < 12; ++k) {
        int u = tid + 256 * k;
        if (u < n * 64) {
            int si = u >> 6, v = u & 63;
            float4 q = x4[(size_t)sgr[k] * 64 + v];
            int off = (v * 8) ^ ((si & 7) << 4);
            Xl[si * 128 + (off >> 2)]     = cvtpk(q.x, q.y);
            Xl[si * 128 + (off >> 2) + 1] = cvtpk(q.z, q.w);
        }
    }

    // ---- stage W slab0 -> buf0, prefetch slab1 ----
    float l1acc = 0.f;
    {
        uint4 pk;
        pk.x = cvtpk(wA[0].x, wA[0].y); pk.y = cvtpk(wA[0].z, wA[0].w);
        pk.z = cvtpk(wA[1].x, wA[1].y); pk.w = cvtpk(wA[1].z, wA[1].w);
        *(uint4*)(&Wl[0][wr * 20 + wh * 8]) = pk;
        pk.x = cvtpk(wA[2].x, wA[2].y); pk.y = cvtpk(wA[2].z, wA[2].w);
        pk.z = cvtpk(wA[3].x, wA[3].y); pk.w = cvtpk(wA[3].z, wA[3].w);
        *(uint4*)(&Wl[0][wr * 20 + wh * 8 + 4]) = pk;
        if (sl == 0) {
            #pragma unroll
            for (int j = 0; j < 4; ++j)
                l1acc += fabsf(wA[j].x) + fabsf(wA[j].y) + fabsf(wA[j].z) + fabsf(wA[j].w);
        }
    }
    #pragma unroll
    for (int j = 0; j < 4; ++j) wB[j] = Wt4[8 + j];       // slab 1
    __syncthreads();                         // Xl + Wl[0] ready

    // ---- K loop: 8 slabs, double-buffered ----
    f32x4 acc[3][2];
    #pragma unroll
    for (int mt = 0; mt < 3; ++mt) {
        acc[mt][0] = (f32x4){0.f, 0.f, 0.f, 0.f};
        acc[mt][1] = (f32x4){0.f, 0.f, 0.f, 0.f};
    }

    #pragma unroll
    for (int kk = 0; kk < 8; ++kk) {
        const unsigned* Wb = Wl[kk & 1];
        bf16x8 bfr0 = *(const bf16x8*)(Wb + (wv * 32 + fr) * 20 + g * 4);
        bf16x8 bfr1 = *(const bf16x8*)(Wb + (wv * 32 + 16 + fr) * 20 + g * 4);
        #pragma unroll
        for (int mt = 0; mt < 3; ++mt) if (mt < mts) {
            int row = mt * 16 + fr;
            bf16x8 afr = *(const bf16x8*)((const char*)Xl + row * 512 + ((kk * 64 + g * 16) ^ ((row & 7) << 4)));
            acc[mt][0] = __builtin_amdgcn_mfma_f32_16x16x32_bf16(afr, bfr0, acc[mt][0], 0, 0, 0);
            acc[mt][1] = __builtin_amdgcn_mfma_f32_16x16x32_bf16(afr, bfr1, acc[mt][1], 0, 0, 0);
        }
        if (kk < 7) {
            const float4* wsrc = (kk & 1) ? wA : wB;       // slab kk+1 regs
            unsigned* wdst = &Wl[(kk + 1) & 1][wr * 20 + wh * 8];
            uint4 pk;
            pk.x = cvtpk(wsrc[0].x, wsrc[0].y); pk.y = cvtpk(wsrc[0].z, wsrc[0].w);
            pk.z = cvtpk(wsrc[1].x, wsrc[1].y); pk.w = cvtpk(wsrc[1].z, wsrc[1].w);
            *(uint4*)(wdst) = pk;
            pk.x = cvtpk(wsrc[2].x, wsrc[2].y); pk.y = cvtpk(wsrc[2].z, wsrc[2].w);
            pk.z = cvtpk(wsrc[3].x, wsrc[3].y); pk.w = cvtpk(wsrc[3].z, wsrc[3].w);
            *(uint4*)(wdst + 4) = pk;
            if (sl == 0) {
                #pragma unroll
                for (int j = 0; j < 4; ++j)
                    l1acc += fabsf(wsrc[j].x) + fabsf(wsrc[j].y) + fabsf(wsrc[j].z) + fabsf(wsrc[j].w);
            }
            if (kk < 6) {
                float4* wld = (kk & 1) ? wB : wA;          // reload with slab kk+2
                #pragma unroll
                for (int j = 0; j < 4; ++j) wld[j] = Wt4[(kk + 2) * 8 + j];
            }
            __syncthreads();
        }
    }

    // ---- W L1 partial (sl==0 blocks; ct splits rows disjointly) ----
    if (sl == 0) {
        float a = wave_reduce_sum(l1acc);
        if (lane == 0) part_w[wv] = a;
    }
    __syncthreads();
    if (sl == 0 && tid == 0)
        l1p[cond * 2 + ct] = (part_w[0] + part_w[1]) + (part_w[2] + part_w[3]);

    // ---- bias add + store unnormalized y ----
    #pragma unroll
    for (int mt = 0; mt < 3; ++mt) if (mt < mts) {
        #pragma unroll
        for (int j = 0; j < 4; ++j) {
            int row = mt * 16 + g * 4 + j;
            if (row < n) {
                int sg = slist[row];
                float* op = out + (size_t)sg * 256 + ct * 128 + wv * 32 + fr;
                op[0]  = acc[mt][0][j] + bias0;
                op[16] = acc[mt][1][j] + bias1;
            }
        }
    }
}

// ---- blocks 0..1023: row L2-normalize (wave per row) ----
// ---- block 1024: finalize embed_norm and mask_norm ----
__global__ __launch_bounds__(256) void k_fin(float* __restrict__ out,
                                             const float* __restrict__ xsqp,
                                             const float* __restrict__ l1p,
                                             const int* __restrict__ cnt4) {
    int tid = threadIdx.x;
    int wv = tid >> 6, lane = tid & 63;
    if (blockIdx.x == 1024) {
        __shared__ float part[4];
        float s = xsqp[tid] + xsqp[tid + 256];
        s = wave_reduce_sum(s);
        if (lane == 0) part[wv] = s;
        __syncthreads();
        if (tid < 64) {
            float l1 = l1p[tid * 2] + l1p[tid * 2 + 1];
            float cnt = (float)((cnt4[tid * 4 + 0] + cnt4[tid * 4 + 1]) + (cnt4[tid * 4 + 2] + cnt4[tid * 4 + 3]));
            float mv = l1 * cnt;
            mv = wave_reduce_sum(mv);
            if (tid == 0) out[BD] = mv;                                               // mask_norm
        }
        if (tid == 0) out[BD + 1] = sqrtf((part[0] + part[1]) + (part[2] + part[3])); // embed_norm
        return;
    }
    int rowv = blockIdx.x * 4 + wv;          // 4096 rows, wave per row
    float4* p = (float4*)out + (size_t)rowv * 64 + lane;
    float4 v = *p;
    float s = v.x * v.x + v.y * v.y + v.z * v.z + v.w * v.w;
    s = wave_reduce_sum(s);
    float inv = 1.0f / fmaxf(sqrtf(s), 1e-10f);
    v.x *= inv; v.y *= inv; v.z *= inv; v.w *= inv;
    *p = v;
}

extern "C" void kernel_launch(void* const* d_in, const int* in_sizes, int n_in,
                              void* d_out, int out_size, void* d_ws, size_t ws_size,
                              hipStream_t stream) {
    const float* x = (const float*)d_in[0];
    const float* W = (const float*)d_in[1];
    const float* b = (const float*)d_in[2];
    const int*   c = (const int*)d_in[3];
    float* out = (float*)d_out;

    float* xsqp = (float*)d_ws;           // 512
    float* l1p  = xsqp + 512;             // 128
    int*   cnt4 = (int*)(l1p + 128);      // 256

    k_main<<<512, 256, 0, stream>>>(W, b, x, c, out, l1p, xsqp, cnt4);
    k_fin<<<1025, 256, 0, stream>>>(out, xsqp, l1p, cnt4);
}

// Round 13
// 18.344 us; speedup vs baseline: 1.7714x; 1.0526x over previous
//
#include <hip/hip_runtime.h>
#include <math.h>

#define B_ 4096
#define D_ 256
#define C_ 64
#define BD (B_*D_)

typedef __attribute__((ext_vector_type(8))) short bf16x8;
typedef __attribute__((ext_vector_type(4))) float f32x4;

__device__ __forceinline__ float wave_reduce_sum(float v) {
    #pragma unroll
    for (int off = 1; off < 64; off <<= 1) v += __shfl_xor(v, off);
    return v;
}

__device__ __forceinline__ unsigned cvtpk(float lo, float hi) {
    unsigned r;
    asm volatile("v_cvt_pk_bf16_f32 %0, %1, %2" : "=v"(r) : "v"(lo), "v"(hi));
    return r;
}

// ---- MFMA kernel: grid = 64 conds x 4 col-quarters x 4 sample-slices = 1024 (4/CU) ----
// Block (cond,ct,sl): y[samples = sl (mod 4) of cond, cols ct*64..+63].
__global__ __launch_bounds__(256, 4) void k_main(const float* __restrict__ W,
                                                 const float* __restrict__ b,
                                                 const float* __restrict__ x,
                                                 const int* __restrict__ c,
                                                 float* __restrict__ out,
                                                 float* __restrict__ l1p,
                                                 float* __restrict__ xsqp,
                                                 int* __restrict__ cnt4) {
    int hw = blockIdx.x;
    int bid = (hw & 7) * 128 + (hw >> 3);   // XCD swizzle: a cond's 16 blocks share an XCD
    int cond = bid >> 4;
    int ct = (bid >> 2) & 3;
    int sl = bid & 3;
    int tid = threadIdx.x;
    int wv = tid >> 6, lane = tid & 63;
    int g = lane >> 4, fr = lane & 15;
    int r = tid >> 2, ch = tid & 3;         // W staging: row 0..63, k-chunk 0..3 (8 floats each)

    // ---- early independent loads: x stripe, c slice, W slab0, bias ----
    const float4* x4 = (const float4*)x;
    int xi = bid * 256 + tid;               // 1 float4 per thread
    float4 xv = x4[xi];
    int4 cvq[4];
    #pragma unroll
    for (int t = 0; t < 4; ++t) cvq[t] = ((const int4*)c)[t * 256 + tid];
    // this block's W rows: cond*65536 + (ct*64 + r)*256 floats; slab kk float4 base kk*8 + ch*2
    const float4* Wt4 = (const float4*)(W + (size_t)cond * 65536) + (size_t)(ct * 64 + r) * 64 + ch * 2;
    float4 wA[2], wB[2];
    wA[0] = Wt4[0]; wA[1] = Wt4[1];         // slab 0 (k 0..31)
    float bias_s = b[cond * 256 + ct * 64 + wv * 16 + fr];

    __shared__ unsigned Xl[48 * 128];        // up to 48 samples x 512B bf16 (XOR swizzled) = 24KB
    __shared__ unsigned Wl[2][64 * 20];      // dbuf W slab: 64 rows x 80B = 10KB
    __shared__ float part_x[4];
    __shared__ float part_w[4];
    __shared__ int slist[48];
    __shared__ int nlist;
    if (tid == 0) nlist = 0;

    // ---- x copy to out tail + sumsq partial ----
    float2* dst = (float2*)(out + BD + 2);
    dst[2 * xi]     = make_float2(xv.x, xv.y);
    dst[2 * xi + 1] = make_float2(xv.z, xv.w);
    float s = xv.x * xv.x + xv.y * xv.y + xv.z * xv.z + xv.w * xv.w;
    s = wave_reduce_sum(s);
    if (lane == 0) part_x[wv] = s;
    __syncthreads();                         // nlist init + part_x visible

    // ---- slice scan: slice sl owns samples i == sl (mod 4) (1024 candidates) ----
    #pragma unroll
    for (int t = 0; t < 4; ++t) {
        int4 q = cvq[t];
        int cc = (sl == 0) ? q.x : (sl == 1) ? q.y : (sl == 2) ? q.z : q.w;
        if (cc == cond) {
            int p = atomicAdd(&nlist, 1);
            if (p < 48) slist[p] = 4 * (t * 256 + tid) + sl;
        }
    }
    // pin W slab0 in regs
    asm volatile("" : "+v"(wA[0].x), "+v"(wA[0].y), "+v"(wA[0].z), "+v"(wA[0].w),
                      "+v"(wA[1].x), "+v"(wA[1].y), "+v"(wA[1].z), "+v"(wA[1].w));
    __syncthreads();
    int n = min(nlist, 48);
    int mts = (n + 15) >> 4;                 // 0..3 sample-tiles
    if (tid == 0) {
        xsqp[bid] = (part_x[0] + part_x[1]) + (part_x[2] + part_x[3]);
        if (ct == 0) cnt4[cond * 4 + sl] = n;
    }

    // ---- stage X: batched gather (slist pre-read -> all loads in flight) ----
    int sgr[12];
    #pragma unroll
    for (int k = 0; k < 12; ++k) sgr[k] = slist[wv + 4 * k];
    #pragma unroll
    for (int k = 0; k < 12; ++k) {
        int u = tid + 256 * k;
        if (u < n * 64) {
            int si = u >> 6, v = u & 63;
            float4 q = x4[(size_t)sgr[k] * 64 + v];
            int off = (v * 8) ^ ((si & 7) << 4);
            Xl[si * 128 + (off >> 2)]     = cvtpk(q.x, q.y);
            Xl[si * 128 + (off >> 2) + 1] = cvtpk(q.z, q.w);
        }
    }

    // ---- stage W slab0 -> buf0, prefetch slab1 ----
    float l1acc = 0.f;
    {
        uint4 pk;
        pk.x = cvtpk(wA[0].x, wA[0].y); pk.y = cvtpk(wA[0].z, wA[0].w);
        pk.z = cvtpk(wA[1].x, wA[1].y); pk.w = cvtpk(wA[1].z, wA[1].w);
        *(uint4*)(&Wl[0][r * 20 + ch * 4]) = pk;
        if (sl == 0)
            l1acc += fabsf(wA[0].x) + fabsf(wA[0].y) + fabsf(wA[0].z) + fabsf(wA[0].w)
                   + fabsf(wA[1].x) + fabsf(wA[1].y) + fabsf(wA[1].z) + fabsf(wA[1].w);
    }
    wB[0] = Wt4[8]; wB[1] = Wt4[9];          // slab 1
    __syncthreads();                         // Xl + Wl[0] ready

    // ---- K loop: 8 slabs, double-buffered ----
    f32x4 acc[3];
    #pragma unroll
    for (int mt = 0; mt < 3; ++mt) acc[mt] = (f32x4){0.f, 0.f, 0.f, 0.f};

    #pragma unroll
    for (int kk = 0; kk < 8; ++kk) {
        const unsigned* Wb = Wl[kk & 1];
        bf16x8 bfr = *(const bf16x8*)(Wb + (wv * 16 + fr) * 20 + g * 4);
        #pragma unroll
        for (int mt = 0; mt < 3; ++mt) if (mt < mts) {
            int row = mt * 16 + fr;
            bf16x8 afr = *(const bf16x8*)((const char*)Xl + row * 512 + ((kk * 64 + g * 16) ^ ((row & 7) << 4)));
            acc[mt] = __builtin_amdgcn_mfma_f32_16x16x32_bf16(afr, bfr, acc[mt], 0, 0, 0);
        }
        if (kk < 7) {
            const float4* wsrc = (kk & 1) ? wA : wB;       // slab kk+1 regs
            uint4 pk;
            pk.x = cvtpk(wsrc[0].x, wsrc[0].y); pk.y = cvtpk(wsrc[0].z, wsrc[0].w);
            pk.z = cvtpk(wsrc[1].x, wsrc[1].y); pk.w = cvtpk(wsrc[1].z, wsrc[1].w);
            *(uint4*)(&Wl[(kk + 1) & 1][r * 20 + ch * 4]) = pk;
            if (sl == 0)
                l1acc += fabsf(wsrc[0].x) + fabsf(wsrc[0].y) + fabsf(wsrc[0].z) + fabsf(wsrc[0].w)
                       + fabsf(wsrc[1].x) + fabsf(wsrc[1].y) + fabsf(wsrc[1].z) + fabsf(wsrc[1].w);
            if (kk < 6) {
                float4* wld = (kk & 1) ? wB : wA;          // reload with slab kk+2
                wld[0] = Wt4[(kk + 2) * 8];
                wld[1] = Wt4[(kk + 2) * 8 + 1];
            }
            __syncthreads();
        }
    }

    // ---- W L1 partial (sl==0 blocks; (cond,ct) quarters are disjoint) ----
    if (sl == 0) {
        float a = wave_reduce_sum(l1acc);
        if (lane == 0) part_w[wv] = a;
    }
    __syncthreads();
    if (sl == 0 && tid == 0)
        l1p[cond * 4 + ct] = (part_w[0] + part_w[1]) + (part_w[2] + part_w[3]);

    // ---- bias add + store unnormalized y ----
    #pragma unroll
    for (int mt = 0; mt < 3; ++mt) if (mt < mts) {
        #pragma unroll
        for (int j = 0; j < 4; ++j) {
            int row = mt * 16 + g * 4 + j;
            if (row < n) {
                int sg = slist[row];
                out[(size_t)sg * 256 + ct * 64 + wv * 16 + fr] = acc[mt][j] + bias_s;
            }
        }
    }
}

// ---- blocks 0..1023: row L2-normalize (wave per row) ----
// ---- block 1024: finalize embed_norm and mask_norm ----
__global__ __launch_bounds__(256) void k_fin(float* __restrict__ out,
                                             const float* __restrict__ xsqp,
                                             const float* __restrict__ l1p,
                                             const int* __restrict__ cnt4) {
    int tid = threadIdx.x;
    int wv = tid >> 6, lane = tid & 63;
    if (blockIdx.x == 1024) {
        __shared__ float part[4];
        float s = 0.f;
        #pragma unroll
        for (int j = 0; j < 4; ++j) s += xsqp[tid * 4 + j];
        s = wave_reduce_sum(s);
        if (lane == 0) part[wv] = s;
        __syncthreads();
        if (tid < 64) {
            float l1 = (l1p[tid * 4 + 0] + l1p[tid * 4 + 1]) + (l1p[tid * 4 + 2] + l1p[tid * 4 + 3]);
            float cnt = (float)((cnt4[tid * 4 + 0] + cnt4[tid * 4 + 1]) + (cnt4[tid * 4 + 2] + cnt4[tid * 4 + 3]));
            float mv = l1 * cnt;
            mv = wave_reduce_sum(mv);
            if (tid == 0) out[BD] = mv;                                               // mask_norm
        }
        if (tid == 0) out[BD + 1] = sqrtf((part[0] + part[1]) + (part[2] + part[3])); // embed_norm
        return;
    }
    int rowv = blockIdx.x * 4 + wv;          // 4096 rows, wave per row
    float4* p = (float4*)out + (size_t)rowv * 64 + lane;
    float4 v = *p;
    float s = v.x * v.x + v.y * v.y + v.z * v.z + v.w * v.w;
    s = wave_reduce_sum(s);
    float inv = 1.0f / fmaxf(sqrtf(s), 1e-10f);
    v.x *= inv; v.y *= inv; v.z *= inv; v.w *= inv;
    *p = v;
}

extern "C" void kernel_launch(void* const* d_in, const int* in_sizes, int n_in,
                              void* d_out, int out_size, void* d_ws, size_t ws_size,
                              hipStream_t stream) {
    const float* x = (const float*)d_in[0];
    const float* W = (const float*)d_in[1];
    const float* b = (const float*)d_in[2];
    const int*   c = (const int*)d_in[3];
    float* out = (float*)d_out;

    float* xsqp = (float*)d_ws;           // 1024
    float* l1p  = xsqp + 1024;            // 256
    int*   cnt4 = (int*)(l1p + 256);      // 256

    k_main<<<1024, 256, 0, stream>>>(W, b, x, c, out, l1p, xsqp, cnt4);
    k_fin<<<1025, 256, 0, stream>>>(out, xsqp, l1p, cnt4);
}